// Round 2
// 357.625 us; speedup vs baseline: 1.0074x; 1.0074x over previous
//
#include <hip/hip_runtime.h>
#include <cstdint>

typedef unsigned short ushort_t;
typedef __bf16 bf16x8 __attribute__((ext_vector_type(8)));
typedef float f32x4 __attribute__((ext_vector_type(4)));

__device__ __forceinline__ unsigned short f2bf(float f) {
  unsigned u = __builtin_bit_cast(unsigned, f);
  u += 0x7FFFu + ((u >> 16) & 1u);   // RNE
  return (unsigned short)(u >> 16);
}
__device__ __forceinline__ float bflo(unsigned u) {  // low bf16 -> f32
  return __builtin_bit_cast(float, u << 16);
}
__device__ __forceinline__ float bfhi(unsigned u) {  // high bf16 -> f32
  return __builtin_bit_cast(float, u & 0xFFFF0000u);
}
// async global->LDS, 16B/lane; LDS dest = wave-uniform base + lane*16
__device__ __forceinline__ void gld16(const void* g, void* l) {
  auto* gp = reinterpret_cast<const __attribute__((address_space(1))) unsigned*>(
      reinterpret_cast<uintptr_t>(g));
  auto* lp = reinterpret_cast<__attribute__((address_space(3))) unsigned*>(
      reinterpret_cast<uintptr_t>(l));
  __builtin_amdgcn_global_load_lds(gp, lp, 16, 0, 0);
}

// ---------------------------------------------------------------------------
// prep_all: UNCHANGED (control).
// ---------------------------------------------------------------------------
__global__ __launch_bounds__(256) void prep_all(
    const float* __restrict__ x, const float* __restrict__ Wq,
    const float* __restrict__ Wk, const float* __restrict__ Wv,
    const float* __restrict__ bq, const float* __restrict__ bk,
    const float* __restrict__ bv, ushort_t* __restrict__ Ax,
    ushort_t* __restrict__ Wt, float* __restrict__ bias) {
  __shared__ ushort_t red[64][65];
  const int b = blockIdx.x;
  const int tid = threadIdx.x;
  if (b < 3072) {
    const int ntile = b % 48, ktile = b / 48;
    const int n0 = ntile * 64, k0 = ktile * 64;
    if (ntile < 16) {
      for (int i = tid; i < 64 * 64; i += 256) {
        const int kk = i >> 6, nn = i & 63;
        const float4 w = *reinterpret_cast<const float4*>(
            Wq + (size_t)(k0 + kk) * 4096 + (size_t)(n0 + nn) * 4);
        red[kk][nn] = f2bf(w.x + w.y + w.z + w.w);
      }
    } else {
      const float* W = (ntile < 32) ? Wk : Wv;
      const int nb = (ntile < 32) ? (n0 - 1024) : (n0 - 2048);
      for (int i = tid; i < 64 * 64; i += 256) {
        const int kk = i >> 6, nn = i & 63;
        red[kk][nn] = f2bf(W[(size_t)(k0 + kk) * 1024 + nb + nn]);
      }
    }
    __syncthreads();
    for (int i = tid; i < 64 * 64; i += 256) {
      const int kk = i & 63, nn = i >> 6;  // coalesced along k
      Wt[(size_t)(n0 + nn) * 4096 + k0 + kk] = red[kk][nn];
    }
  } else if (b < 11264) {
    const size_t i = ((size_t)(b - 3072) * 256 + tid) * 8;
    const float4 a = *reinterpret_cast<const float4*>(x + i);
    const float4 c = *reinterpret_cast<const float4*>(x + i + 4);
    union { ushort_t u[8]; uint4 v; } pk;
    pk.u[0] = f2bf(a.x); pk.u[1] = f2bf(a.y); pk.u[2] = f2bf(a.z); pk.u[3] = f2bf(a.w);
    pk.u[4] = f2bf(c.x); pk.u[5] = f2bf(c.y); pk.u[6] = f2bf(c.z); pk.u[7] = f2bf(c.w);
    *reinterpret_cast<uint4*>(Ax + i) = pk.v;
  } else {
    const int n = (b - 11264) * 256 + tid;  // 0..3071
    float v;
    if (n < 1024) {
      const float4 w = *reinterpret_cast<const float4*>(bq + (size_t)n * 4);
      v = w.x + w.y + w.z + w.w;
    } else if (n < 2048) {
      v = bk[n - 1024];
    } else {
      v = bv[n - 2048];
    }
    bias[n] = v;
  }
}

// ---------------------------------------------------------------------------
// gemm_qkv v3: the VERIFIED 128x128 kernel (1004 TF, 0 bank conflicts) with
// ONLY the sync structure changed to the T3-minimum 2-phase recipe:
//   - double-buffered LDS (2 x 32 KB; still 2 blocks/CU)
//   - stage tile t+1 BEFORE computing tile t (latency hides under compute)
//   - one raw s_barrier per K-step; vmcnt(0) AFTER the MFMAs (was: two
//     __syncthreads with full vmcnt(0)+lgkmcnt(0) drains, stage latency
//     serially exposed)
// Ledger: at the flip the only outstanding VMEM ops are this wave's 8 stage
// loads; ds_reads of a buffer retire before the barrier preceding its
// overwrite (MFMA consumes the values -> compiler lgkmcnt). No partial-tile
// publish points exist, unlike the failed R1 schedule.
// ---------------------------------------------------------------------------
#define WAITV0() asm volatile("s_waitcnt vmcnt(0)" ::: "memory")
#define BARRIER()                         \
  do {                                    \
    __builtin_amdgcn_s_barrier();         \
    asm volatile("" ::: "memory");        \
    __builtin_amdgcn_sched_barrier(0);    \
  } while (0)

__global__ __launch_bounds__(256, 2) void gemm_qkv(const ushort_t* __restrict__ A,
                                                   const ushort_t* __restrict__ Bt,
                                                   const float* __restrict__ bias,
                                                   ushort_t* __restrict__ C) {
  __shared__ ushort_t As[2][128 * 64];  // 2 x 16 KB
  __shared__ ushort_t Bs[2][128 * 64];  // 2 x 16 KB
  const int tid = threadIdx.x;
  const int lane = tid & 63, wave = tid >> 6;
  const int M0 = blockIdx.y * 128, N0 = blockIdx.x * 128;

  const int rik = lane >> 3;         // row within 8-row chunk
  const int gch = (lane & 7) ^ rik;  // swizzled global k-chunk (involution)
  const ushort_t* aG = A + (size_t)(M0 + wave * 32 + rik) * 4096 + gch * 8;
  const ushort_t* bG = Bt + (size_t)(N0 + wave * 32 + rik) * 4096 + gch * 8;

  const int wm = wave >> 1, wn = wave & 1;
  const int quad = lane >> 4, l15 = lane & 15;

  f32x4 acc[4][4];
  const f32x4 z = {0.f, 0.f, 0.f, 0.f};
#pragma unroll
  for (int mi = 0; mi < 4; ++mi)
#pragma unroll
    for (int ni = 0; ni < 4; ++ni) acc[mi][ni] = z;

  auto stage = [&](int bb, int kt) {
    const int ko = kt * 64;
#pragma unroll
    for (int q = 0; q < 4; ++q)
      gld16(aG + ko + q * (8 * 4096), &As[bb][(wave * 4 + q) * 512]);
#pragma unroll
    for (int q = 0; q < 4; ++q)
      gld16(bG + ko + q * (8 * 4096), &Bs[bb][(wave * 4 + q) * 512]);
  };

  // prologue: stage tile 0 into buf0, publish.
  stage(0, 0);
  WAITV0();
  BARRIER();

  for (int kt = 0; kt < 64; ++kt) {
    const int bb = kt & 1;
    if (kt < 63) stage(bb ^ 1, kt + 1);  // issue next-tile loads FIRST
#pragma unroll
    for (int ks = 0; ks < 2; ++ks) {
      bf16x8 af[4], bfr[4];
#pragma unroll
      for (int mi = 0; mi < 4; ++mi) {
        const int row = wm * 64 + mi * 16 + l15;
        const int ch = ((ks * 4 + quad) ^ (row & 7)) * 8;
        af[mi] = *reinterpret_cast<const bf16x8*>(&As[bb][row * 64 + ch]);
      }
#pragma unroll
      for (int ni = 0; ni < 4; ++ni) {
        const int row = wn * 64 + ni * 16 + l15;
        const int ch = ((ks * 4 + quad) ^ (row & 7)) * 8;
        bfr[ni] = *reinterpret_cast<const bf16x8*>(&Bs[bb][row * 64 + ch]);
      }
      __builtin_amdgcn_s_setprio(1);
#pragma unroll
      for (int mi = 0; mi < 4; ++mi)
#pragma unroll
        for (int ni = 0; ni < 4; ++ni)
          acc[mi][ni] =
              __builtin_amdgcn_mfma_f32_16x16x32_bf16(af[mi], bfr[ni], acc[mi][ni], 0, 0, 0);
      __builtin_amdgcn_s_setprio(0);
    }
    // drain AFTER compute: next tile's loads had the whole tile to land.
    WAITV0();
    BARRIER();
  }

#pragma unroll
  for (int ni = 0; ni < 4; ++ni) {
    const int cc = N0 + wn * 64 + ni * 16 + l15;
    const float bn = bias[cc];
#pragma unroll
    for (int mi = 0; mi < 4; ++mi) {
      const int r0 = M0 + wm * 64 + mi * 16 + quad * 4;
#pragma unroll
      for (int r = 0; r < 4; ++r)
        C[(size_t)(r0 + r) * 3072 + cc] = f2bf(acc[mi][ni][r] + bn);
    }
  }
}

// ---------------------------------------------------------------------------
// attn_tok: UNCHANGED (control).
// ---------------------------------------------------------------------------
__global__ __launch_bounds__(256, 4) void attn_tok(const ushort_t* __restrict__ C,
                                                   float* __restrict__ out) {
  __shared__ uint4 kv4[4][256];  // [wave][k rows 0..127 | v rows 128..255]
  const int tid = threadIdx.x;
  const int lane = tid & 63, wv = tid >> 6;
  const int t = blockIdx.x * 4 + wv;
  const ushort_t* Crow = C + (size_t)t * 3072;

  const uint4* src = reinterpret_cast<const uint4*>(Crow + 1024);
#pragma unroll
  for (int r = 0; r < 4; ++r) kv4[wv][r * 64 + lane] = src[r * 64 + lane];
  __syncthreads();

  const uint4 q01 = *reinterpret_cast<const uint4*>(Crow + lane * 16);
  const uint4 q23 = *reinterpret_cast<const uint4*>(Crow + lane * 16 + 8);
  float qa[8], qb[8];
  qa[0] = bflo(q01.x); qa[1] = bfhi(q01.x); qa[2] = bflo(q01.y); qa[3] = bfhi(q01.y);
  qa[4] = bflo(q01.z); qa[5] = bfhi(q01.z); qa[6] = bflo(q01.w); qa[7] = bfhi(q01.w);
  qb[0] = bflo(q23.x); qb[1] = bfhi(q23.x); qb[2] = bflo(q23.y); qb[3] = bfhi(q23.y);
  qb[4] = bflo(q23.z); qb[5] = bfhi(q23.z); qb[6] = bflo(q23.w); qb[7] = bfhi(q23.w);

  const uint4* kvw = kv4[wv];
  const float sc = 0.08838834764831845f;  // 1/sqrt(128)
  float oa[8], ob[8];
#pragma unroll
  for (int j = 0; j < 8; ++j) { oa[j] = 0.f; ob[j] = 0.f; }
  float l0 = 0.f, l1 = 0.f;

#pragma unroll 2
  for (int e = 0; e < 128; ++e) {
    const uint4 kr = kvw[e];
    float kf[8];
    kf[0] = bflo(kr.x); kf[1] = bfhi(kr.x); kf[2] = bflo(kr.y); kf[3] = bfhi(kr.y);
    kf[4] = bflo(kr.z); kf[5] = bfhi(kr.z); kf[6] = bflo(kr.w); kf[7] = bfhi(kr.w);
    float s0 = 0.f, s1 = 0.f;
#pragma unroll
    for (int j = 0; j < 8; ++j) { s0 += qa[j] * kf[j]; s1 += qb[j] * kf[j]; }
    const float p0 = __expf(s0 * sc);
    const float p1 = __expf(s1 * sc);
    l0 += p0; l1 += p1;
    const uint4 vr = kvw[128 + e];
    float vf[8];
    vf[0] = bflo(vr.x); vf[1] = bfhi(vr.x); vf[2] = bflo(vr.y); vf[3] = bfhi(vr.y);
    vf[4] = bflo(vr.z); vf[5] = bfhi(vr.z); vf[6] = bflo(vr.w); vf[7] = bfhi(vr.w);
#pragma unroll
    for (int j = 0; j < 8; ++j) { oa[j] += p0 * vf[j]; ob[j] += p1 * vf[j]; }
  }

  const float i0 = 1.f / l0, i1 = 1.f / l1;
  float4* dst = reinterpret_cast<float4*>(out + (size_t)t * 4096 + (size_t)lane * 64);
#pragma unroll
  for (int j = 0; j < 8; ++j) {
    const float w = oa[j] * i0;
    dst[j] = make_float4(w, w, w, w);
  }
#pragma unroll
  for (int j = 0; j < 8; ++j) {
    const float w = ob[j] * i1;
    dst[8 + j] = make_float4(w, w, w, w);
  }
}

extern "C" void kernel_launch(void* const* d_in, const int* in_sizes, int n_in,
                              void* d_out, int out_size, void* d_ws, size_t ws_size,
                              hipStream_t stream) {
  const float* x  = (const float*)d_in[0];  // [2,2048,4096] fp32
  const float* Wq = (const float*)d_in[1];  // [4096,128,32]
  const float* bq = (const float*)d_in[2];  // [128,32]
  const float* Wk = (const float*)d_in[3];  // [4096,128,8]
  const float* bk = (const float*)d_in[4];  // [128,8]
  const float* Wv = (const float*)d_in[5];  // [4096,128,8]
  const float* bv = (const float*)d_in[6];  // [128,8]
  float* out = (float*)d_out;               // [4096][4096] fp32 = 64 MB

  // d_out doubles as scratch until attn_tok overwrites it:
  //   [0,32M): Ax bf16; [32M,56M): Wt bf16; [56M,+12K): bias fp32.
  // d_ws: Cmat bf16 [4096][3072] (24 MB).
  ushort_t* Ax = (ushort_t*)d_out;
  ushort_t* Wt = Ax + (size_t)4096 * 4096;
  float* bias = (float*)(Wt + (size_t)3072 * 4096);
  ushort_t* Cmat = (ushort_t*)d_ws;

  prep_all<<<dim3(11276), 256, 0, stream>>>(x, Wq, Wk, Wv, bq, bk, bv, Ax, Wt, bias);
  gemm_qkv<<<dim3(24, 32), 256, 0, stream>>>(Ax, Wt, bias, Cmat);
  attn_tok<<<dim3(1024), 256, 0, stream>>>(Cmat, out);
}

// Round 3
// 347.882 us; speedup vs baseline: 1.0356x; 1.0280x over previous
//
#include <hip/hip_runtime.h>
#include <cstdint>

typedef unsigned short ushort_t;
typedef __bf16 bf16x8 __attribute__((ext_vector_type(8)));
typedef float f32x4 __attribute__((ext_vector_type(4)));

__device__ __forceinline__ unsigned short f2bf(float f) {
  unsigned u = __builtin_bit_cast(unsigned, f);
  u += 0x7FFFu + ((u >> 16) & 1u);   // RNE
  return (unsigned short)(u >> 16);
}
__device__ __forceinline__ float bflo(unsigned u) {  // low bf16 -> f32
  return __builtin_bit_cast(float, u << 16);
}
__device__ __forceinline__ float bfhi(unsigned u) {  // high bf16 -> f32
  return __builtin_bit_cast(float, u & 0xFFFF0000u);
}
// async global->LDS, 16B/lane; LDS dest = wave-uniform base + lane*16
__device__ __forceinline__ void gld16(const void* g, void* l) {
  auto* gp = reinterpret_cast<const __attribute__((address_space(1))) unsigned*>(
      reinterpret_cast<uintptr_t>(g));
  auto* lp = reinterpret_cast<__attribute__((address_space(3))) unsigned*>(
      reinterpret_cast<uintptr_t>(l));
  __builtin_amdgcn_global_load_lds(gp, lp, 16, 0, 0);
}

// ---------------------------------------------------------------------------
// prep_all: UNCHANGED (control).
// ---------------------------------------------------------------------------
__global__ __launch_bounds__(256) void prep_all(
    const float* __restrict__ x, const float* __restrict__ Wq,
    const float* __restrict__ Wk, const float* __restrict__ Wv,
    const float* __restrict__ bq, const float* __restrict__ bk,
    const float* __restrict__ bv, ushort_t* __restrict__ Ax,
    ushort_t* __restrict__ Wt, float* __restrict__ bias) {
  __shared__ ushort_t red[64][65];
  const int b = blockIdx.x;
  const int tid = threadIdx.x;
  if (b < 3072) {
    const int ntile = b % 48, ktile = b / 48;
    const int n0 = ntile * 64, k0 = ktile * 64;
    if (ntile < 16) {
      for (int i = tid; i < 64 * 64; i += 256) {
        const int kk = i >> 6, nn = i & 63;
        const float4 w = *reinterpret_cast<const float4*>(
            Wq + (size_t)(k0 + kk) * 4096 + (size_t)(n0 + nn) * 4);
        red[kk][nn] = f2bf(w.x + w.y + w.z + w.w);
      }
    } else {
      const float* W = (ntile < 32) ? Wk : Wv;
      const int nb = (ntile < 32) ? (n0 - 1024) : (n0 - 2048);
      for (int i = tid; i < 64 * 64; i += 256) {
        const int kk = i >> 6, nn = i & 63;
        red[kk][nn] = f2bf(W[(size_t)(k0 + kk) * 1024 + nb + nn]);
      }
    }
    __syncthreads();
    for (int i = tid; i < 64 * 64; i += 256) {
      const int kk = i & 63, nn = i >> 6;  // coalesced along k
      Wt[(size_t)(n0 + nn) * 4096 + k0 + kk] = red[kk][nn];
    }
  } else if (b < 11264) {
    const size_t i = ((size_t)(b - 3072) * 256 + tid) * 8;
    const float4 a = *reinterpret_cast<const float4*>(x + i);
    const float4 c = *reinterpret_cast<const float4*>(x + i + 4);
    union { ushort_t u[8]; uint4 v; } pk;
    pk.u[0] = f2bf(a.x); pk.u[1] = f2bf(a.y); pk.u[2] = f2bf(a.z); pk.u[3] = f2bf(a.w);
    pk.u[4] = f2bf(c.x); pk.u[5] = f2bf(c.y); pk.u[6] = f2bf(c.z); pk.u[7] = f2bf(c.w);
    *reinterpret_cast<uint4*>(Ax + i) = pk.v;
  } else {
    const int n = (b - 11264) * 256 + tid;  // 0..3071
    float v;
    if (n < 1024) {
      const float4 w = *reinterpret_cast<const float4*>(bq + (size_t)n * 4);
      v = w.x + w.y + w.z + w.w;
    } else if (n < 2048) {
      v = bk[n - 1024];
    } else {
      v = bv[n - 2048];
    }
    bias[n] = v;
  }
}

// ---------------------------------------------------------------------------
// gemm_qkv v4: 256x192 tile, BK=64, 8 waves (2M x 4N), per-wave 128x48 out.
// Geometry rationale (cycle model):
//   - reads/MFMA drops 0.5 -> 0.458 (LDS pipe was co-bottleneck at 128^2)
//   - grid 16x16 = 256 blocks = exactly 1 block/CU (100% CU fill)
//   - L2 panel traffic 1.5 GB -> 448 MB
// Schedule per K-tile: front-load ALL stage loads for t+1 (window = full
// tile ~1800cy >> 900cy HBM latency, so the per-tile vmcnt(0) gate is
// stall-free by construction), 2 x (ds_read frags + 24 MFMA), vmcnt(0),
// ONE raw s_barrier. Ledger: nb's prior-tile ds_reads retired before the
// previous barrier (they feed MFMAs that precede it); the gate + barrier
// publishes tile t+1 block-wide. LDS swizzle unchanged (proven, 0 conflict):
// physical chunk = logical ^ (row&7); stage rik == row&7 for A and B
// (wave*32 and wave*24 are both 0 mod 8).
// ---------------------------------------------------------------------------
#define WAITV0() asm volatile("s_waitcnt vmcnt(0)" ::: "memory")
#define BARRIER()                         \
  do {                                    \
    __builtin_amdgcn_s_barrier();         \
    asm volatile("" ::: "memory");        \
    __builtin_amdgcn_sched_barrier(0);    \
  } while (0)

__global__ __launch_bounds__(512, 2) void gemm_qkv(const ushort_t* __restrict__ A,
                                                   const ushort_t* __restrict__ Bt,
                                                   const float* __restrict__ bias,
                                                   ushort_t* __restrict__ C) {
  __shared__ ushort_t As[2][256 * 64];  // 2 x 32 KB
  __shared__ ushort_t Bs[2][192 * 64];  // 2 x 24 KB   (total 112 KB)
  const int tid = threadIdx.x;
  const int lane = tid & 63, wave = tid >> 6;  // 8 waves

  // bijective XCD swizzle (256 blocks, 256 % 8 == 0)
  const int id = blockIdx.x;
  const int wg = (id & 7) * 32 + (id >> 3);
  const int M0 = (wg >> 4) * 256, N0 = (wg & 15) * 192;

  const int rik = lane >> 3;         // row within 8-row chunk
  const int gch = (lane & 7) ^ rik;  // pre-swizzled global k-chunk (involution)
  const ushort_t* aG = A + (size_t)(M0 + wave * 32 + rik) * 4096 + gch * 8;
  const ushort_t* bG = Bt + (size_t)(N0 + wave * 24 + rik) * 4096 + gch * 8;

  const int wm = wave >> 2, wn = wave & 3;  // 2M x 4N wave grid
  const int quad = lane >> 4, l15 = lane & 15;

  f32x4 acc[8][3];
  const f32x4 z = {0.f, 0.f, 0.f, 0.f};
#pragma unroll
  for (int mi = 0; mi < 8; ++mi)
#pragma unroll
    for (int ni = 0; ni < 3; ++ni) acc[mi][ni] = z;

  auto stage = [&](int bb, int kt) {
    const int ko = kt * 64;
#pragma unroll
    for (int q = 0; q < 4; ++q)  // A: wave stages rows wave*32 + q*8 + rik
      gld16(aG + ko + (size_t)q * (8 * 4096), &As[bb][(wave * 4 + q) * 512]);
#pragma unroll
    for (int q = 0; q < 3; ++q)  // B: wave stages rows wave*24 + q*8 + rik
      gld16(bG + ko + (size_t)q * (8 * 4096), &Bs[bb][(wave * 3 + q) * 512]);
  };

  // prologue: stage tile 0 into buf0, publish.
  stage(0, 0);
  WAITV0();
  BARRIER();

  for (int kt = 0; kt < 64; ++kt) {
    const int bb = kt & 1;
    if (kt < 63) stage(bb ^ 1, kt + 1);  // front-load next tile's 7 loads
#pragma unroll
    for (int ks = 0; ks < 2; ++ks) {
      bf16x8 af[8], bfr[3];
#pragma unroll
      for (int mi = 0; mi < 8; ++mi) {
        const int row = wm * 128 + mi * 16 + l15;
        const int ch = ((ks * 4 + quad) ^ (row & 7)) * 8;
        af[mi] = *reinterpret_cast<const bf16x8*>(&As[bb][row * 64 + ch]);
      }
#pragma unroll
      for (int ni = 0; ni < 3; ++ni) {
        const int row = wn * 48 + ni * 16 + l15;
        const int ch = ((ks * 4 + quad) ^ (row & 7)) * 8;
        bfr[ni] = *reinterpret_cast<const bf16x8*>(&Bs[bb][row * 64 + ch]);
      }
      __builtin_amdgcn_s_setprio(1);
#pragma unroll
      for (int mi = 0; mi < 8; ++mi)
#pragma unroll
        for (int ni = 0; ni < 3; ++ni)
          acc[mi][ni] =
              __builtin_amdgcn_mfma_f32_16x16x32_bf16(af[mi], bfr[ni], acc[mi][ni], 0, 0, 0);
      __builtin_amdgcn_s_setprio(0);
    }
    // gate: own 7 loads were issued a full tile (~1800cy) ago -> no stall.
    WAITV0();
    BARRIER();
  }

#pragma unroll
  for (int ni = 0; ni < 3; ++ni) {
    const int cc = N0 + wn * 48 + ni * 16 + l15;
    const float bn = bias[cc];
#pragma unroll
    for (int mi = 0; mi < 8; ++mi) {
      const int r0 = M0 + wm * 128 + mi * 16 + quad * 4;
#pragma unroll
      for (int r = 0; r < 4; ++r)
        C[(size_t)(r0 + r) * 3072 + cc] = f2bf(acc[mi][ni][r] + bn);
    }
  }
}

// ---------------------------------------------------------------------------
// attn_tok: UNCHANGED (control).
// ---------------------------------------------------------------------------
__global__ __launch_bounds__(256, 4) void attn_tok(const ushort_t* __restrict__ C,
                                                   float* __restrict__ out) {
  __shared__ uint4 kv4[4][256];  // [wave][k rows 0..127 | v rows 128..255]
  const int tid = threadIdx.x;
  const int lane = tid & 63, wv = tid >> 6;
  const int t = blockIdx.x * 4 + wv;
  const ushort_t* Crow = C + (size_t)t * 3072;

  const uint4* src = reinterpret_cast<const uint4*>(Crow + 1024);
#pragma unroll
  for (int r = 0; r < 4; ++r) kv4[wv][r * 64 + lane] = src[r * 64 + lane];
  __syncthreads();

  const uint4 q01 = *reinterpret_cast<const uint4*>(Crow + lane * 16);
  const uint4 q23 = *reinterpret_cast<const uint4*>(Crow + lane * 16 + 8);
  float qa[8], qb[8];
  qa[0] = bflo(q01.x); qa[1] = bfhi(q01.x); qa[2] = bflo(q01.y); qa[3] = bfhi(q01.y);
  qa[4] = bflo(q01.z); qa[5] = bfhi(q01.z); qa[6] = bflo(q01.w); qa[7] = bfhi(q01.w);
  qb[0] = bflo(q23.x); qb[1] = bfhi(q23.x); qb[2] = bflo(q23.y); qb[3] = bfhi(q23.y);
  qb[4] = bflo(q23.z); qb[5] = bfhi(q23.z); qb[6] = bflo(q23.w); qb[7] = bfhi(q23.w);

  const uint4* kvw = kv4[wv];
  const float sc = 0.08838834764831845f;  // 1/sqrt(128)
  float oa[8], ob[8];
#pragma unroll
  for (int j = 0; j < 8; ++j) { oa[j] = 0.f; ob[j] = 0.f; }
  float l0 = 0.f, l1 = 0.f;

#pragma unroll 2
  for (int e = 0; e < 128; ++e) {
    const uint4 kr = kvw[e];
    float kf[8];
    kf[0] = bflo(kr.x); kf[1] = bfhi(kr.x); kf[2] = bflo(kr.y); kf[3] = bfhi(kr.y);
    kf[4] = bflo(kr.z); kf[5] = bfhi(kr.z); kf[6] = bflo(kr.w); kf[7] = bfhi(kr.w);
    float s0 = 0.f, s1 = 0.f;
#pragma unroll
    for (int j = 0; j < 8; ++j) { s0 += qa[j] * kf[j]; s1 += qb[j] * kf[j]; }
    const float p0 = __expf(s0 * sc);
    const float p1 = __expf(s1 * sc);
    l0 += p0; l1 += p1;
    const uint4 vr = kvw[128 + e];
    float vf[8];
    vf[0] = bflo(vr.x); vf[1] = bfhi(vr.x); vf[2] = bflo(vr.y); vf[3] = bfhi(vr.y);
    vf[4] = bflo(vr.z); vf[5] = bfhi(vr.z); vf[6] = bflo(vr.w); vf[7] = bfhi(vr.w);
#pragma unroll
    for (int j = 0; j < 8; ++j) { oa[j] += p0 * vf[j]; ob[j] += p1 * vf[j]; }
  }

  const float i0 = 1.f / l0, i1 = 1.f / l1;
  float4* dst = reinterpret_cast<float4*>(out + (size_t)t * 4096 + (size_t)lane * 64);
#pragma unroll
  for (int j = 0; j < 8; ++j) {
    const float w = oa[j] * i0;
    dst[j] = make_float4(w, w, w, w);
  }
#pragma unroll
  for (int j = 0; j < 8; ++j) {
    const float w = ob[j] * i1;
    dst[8 + j] = make_float4(w, w, w, w);
  }
}

extern "C" void kernel_launch(void* const* d_in, const int* in_sizes, int n_in,
                              void* d_out, int out_size, void* d_ws, size_t ws_size,
                              hipStream_t stream) {
  const float* x  = (const float*)d_in[0];  // [2,2048,4096] fp32
  const float* Wq = (const float*)d_in[1];  // [4096,128,32]
  const float* bq = (const float*)d_in[2];  // [128,32]
  const float* Wk = (const float*)d_in[3];  // [4096,128,8]
  const float* bk = (const float*)d_in[4];  // [128,8]
  const float* Wv = (const float*)d_in[5];  // [4096,128,8]
  const float* bv = (const float*)d_in[6];  // [128,8]
  float* out = (float*)d_out;               // [4096][4096] fp32 = 64 MB

  // d_out doubles as scratch until attn_tok overwrites it:
  //   [0,32M): Ax bf16; [32M,56M): Wt bf16; [56M,+12K): bias fp32.
  // d_ws: Cmat bf16 [4096][3072] (24 MB).
  ushort_t* Ax = (ushort_t*)d_out;
  ushort_t* Wt = Ax + (size_t)4096 * 4096;
  float* bias = (float*)(Wt + (size_t)3072 * 4096);
  ushort_t* Cmat = (ushort_t*)d_ws;

  prep_all<<<dim3(11276), 256, 0, stream>>>(x, Wq, Wk, Wv, bq, bk, bv, Ax, Wt, bias);
  gemm_qkv<<<dim3(256), 512, 0, stream>>>(Ax, Wt, bias, Cmat);
  attn_tok<<<dim3(1024), 256, 0, stream>>>(Cmat, out);
}